// Round 16
// baseline (2051.139 us; speedup 1.0000x reference)
//
#include <hip/hip_runtime.h>
#include <math.h>

// Problem constants
#define NB 32      // batch
#define TE 128     // encoder length
#define NT 64      // decoder steps
#define HH 1024    // hidden
#define EE 512     // embed dim
#define VV 32000   // vocab
#define GG 4096    // 4*H
#define WQN 5120   // Wa(1024) + W_hh(4096) output cols
#define NBLK 512   // four independent 128-block quarter-pipelines

typedef __attribute__((ext_vector_type(8))) short bh8;     // 8 bf16
typedef __attribute__((ext_vector_type(4))) float fx4;     // MFMA accumulator
typedef __attribute__((ext_vector_type(4))) unsigned ux4;  // 16B raw
typedef __attribute__((ext_vector_type(4))) float fv4;     // 16B float (asm-safe)

__device__ __forceinline__ float tanh_fast(float x) {
  float e = __expf(2.f * x);
  return 1.f - 2.f / (e + 1.f);
}
__device__ __forceinline__ float sigf(float x) { return 1.f / (1.f + __expf(-x)); }
__device__ __forceinline__ ushort f2bf(float x) {
  union { float f; unsigned u; } v; v.f = x;
  unsigned r = v.u + 0x7fffu + ((v.u >> 16) & 1u);
  return (ushort)(r >> 16);
}
__device__ __forceinline__ float bf2f(ushort u) {
  return __uint_as_float(((unsigned)u) << 16);
}

// agent-scope relaxed atomics for small scattered coherent ops
__device__ __forceinline__ void st_f32(float* p, float v) {
  __hip_atomic_store(p, v, __ATOMIC_RELAXED, __HIP_MEMORY_SCOPE_AGENT);
}
__device__ __forceinline__ float ld_f32(const float* p) {
  return __hip_atomic_load(p, __ATOMIC_RELAXED, __HIP_MEMORY_SCOPE_AGENT);
}
__device__ __forceinline__ void st_u32(unsigned* p, unsigned v) {
  __hip_atomic_store(p, v, __ATOMIC_RELAXED, __HIP_MEMORY_SCOPE_AGENT);
}
__device__ __forceinline__ unsigned ld_u32(const unsigned* p) {
  return __hip_atomic_load(p, __ATOMIC_RELAXED, __HIP_MEMORY_SCOPE_AGENT);
}

// h_u32 <- packed bf16 pairs of encoder_hidden[0]
__global__ void k_init(const float* __restrict__ eh, unsigned* __restrict__ h_u32) {
  int i = blockIdx.x * 256 + threadIdx.x;  // 16384
  float a = eh[i * 2], b = eh[i * 2 + 1];
  h_u32[i] = (unsigned)f2bf(a) | ((unsigned)f2bf(b) << 16);
}

// emb_bf[t*NB+b][e] = bf16(emb_table[tok(t,b)][e]); padding_idx=0 -> 0; tok(0,b)=SOS=1
__global__ void k_emb(const int* __restrict__ tgt, const float* __restrict__ etab,
                      ushort* __restrict__ emb_bf) {
  int idx = blockIdx.x * 256 + threadIdx.x;  // 1048576
  int e = idx & (EE - 1);
  int tb = idx >> 9;
  int b = tb & (NB - 1);
  int t = tb >> 5;
  int tok = (t == 0) ? 1 : tgt[b * NT + (t - 1)];
  emb_bf[idx] = (tok == 0) ? (ushort)0 : f2bf(etab[(size_t)tok * EE + e]);
}

__global__ void k_f2b(const float* __restrict__ s, ushort* __restrict__ d, int n4) {
  int i = blockIdx.x * 256 + threadIdx.x;
  if (i >= n4) return;
  float4 v = *(const float4*)(s + (size_t)i * 4);
  *(ushort4*)(d + (size_t)i * 4) = make_ushort4(f2bf(v.x), f2bf(v.y), f2bf(v.z), f2bf(v.w));
}

__global__ void k_f2b_s(const float* __restrict__ s, int ld, int off, int w4,
                        ushort* __restrict__ d, int n) {
  int i = blockIdx.x * 256 + threadIdx.x;
  if (i >= n) return;
  int r = i / w4, c = (i - r * w4) * 4;
  float4 v = *(const float4*)(s + (size_t)r * ld + off + c);
  *(ushort4*)(d + (size_t)r * (w4 * 4) + c) = make_ushort4(f2bf(v.x), f2bf(v.y), f2bf(v.z), f2bf(v.w));
}

// ---- bf16 MFMA GEMM (m97 structure): 128x128 tile, BK=32, 4 waves 2x2 ----
__device__ __forceinline__ void stage_pair(const ushort* A, int lda, const ushort* B, int ldb,
    int m0, int n0, int k0, ushort* ldsA, ushort* ldsB, int tid) {
  const int w = tid >> 6;
  const int row = tid >> 2;
  const int kq = (tid & 3) * 8;
  const ushort* ga = A + (size_t)(m0 + row) * lda + k0 + kq;
  const ushort* gb = B + (size_t)(n0 + row) * ldb + k0 + kq;
  ushort* la = ldsA + w * 512;
  ushort* lb = ldsB + w * 512;
  __builtin_amdgcn_global_load_lds((const __attribute__((address_space(1))) void*)ga,
      (__attribute__((address_space(3))) void*)la, 16, 0, 0);
  __builtin_amdgcn_global_load_lds((const __attribute__((address_space(1))) void*)(ga + (size_t)64 * lda),
      (__attribute__((address_space(3))) void*)(la + 2048), 16, 0, 0);
  __builtin_amdgcn_global_load_lds((const __attribute__((address_space(1))) void*)gb,
      (__attribute__((address_space(3))) void*)lb, 16, 0, 0);
  __builtin_amdgcn_global_load_lds((const __attribute__((address_space(1))) void*)(gb + (size_t)64 * ldb),
      (__attribute__((address_space(3))) void*)(lb + 2048), 16, 0, 0);
}

__global__ __launch_bounds__(256) void k_gemm_bf16(
    const ushort* __restrict__ A, int lda,
    const ushort* __restrict__ B, int ldb,
    const float* __restrict__ b1, const float* __restrict__ b2,
    void* __restrict__ Cv, int ldc, int K, int perm, int obf, int swz) {
  __shared__ ushort lds[2][2][4096];
  const int tid = threadIdx.x;
  const int lane = tid & 63, w = tid >> 6;
  int m0, n0;
  if (swz) {
    const int bid = blockIdx.y * gridDim.x + blockIdx.x;
    m0 = (bid & 15) * 128;
    n0 = (bid >> 4) * 128;
  } else {
    m0 = blockIdx.y * 128;
    n0 = blockIdx.x * 128;
  }
  const int wm = (w >> 1) * 64, wn = (w & 1) * 64;
  fx4 acc[4][4] = {};
  stage_pair(A, lda, B, ldb, m0, n0, 0, lds[0][0], lds[0][1], tid);
  __syncthreads();
  const int nk = K >> 5;
  const int ko = (lane >> 4) * 8;
  const int rA = wm + (lane & 15);
  const int rB = wn + (lane & 15);
  for (int ks = 0; ks < nk; ++ks) {
    const int cur = ks & 1;
    if (ks + 1 < nk)
      stage_pair(A, lda, B, ldb, m0, n0, (ks + 1) << 5, lds[cur ^ 1][0], lds[cur ^ 1][1], tid);
    bh8 af[4], bfr[4];
#pragma unroll
    for (int f = 0; f < 4; ++f) {
      af[f]  = *(const bh8*)(&lds[cur][0][(rA + f * 16) * 32 + ko]);
      bfr[f] = *(const bh8*)(&lds[cur][1][(rB + f * 16) * 32 + ko]);
    }
#pragma unroll
    for (int i = 0; i < 4; ++i)
#pragma unroll
      for (int j = 0; j < 4; ++j)
        acc[i][j] = __builtin_amdgcn_mfma_f32_16x16x32_bf16(af[i], bfr[j], acc[i][j], 0, 0, 0);
    __syncthreads();
  }
  float* Cf = (float*)Cv;
  ushort* Cb = (ushort*)Cv;
#pragma unroll
  for (int j = 0; j < 4; ++j) {
    const int col = n0 + wn + j * 16 + (lane & 15);
    const float bv = (b1 ? b1[col] : 0.f) + (b2 ? b2[col] : 0.f);
#pragma unroll
    for (int i = 0; i < 4; ++i) {
      const int mb = m0 + wm + i * 16 + (lane >> 4) * 4;
#pragma unroll
      for (int r = 0; r < 4; ++r) {
        const int m = mb + r;
        const size_t orow = perm ? ((size_t)(m & 31) * 64 + (m >> 5)) : (size_t)m;
        const float v = acc[i][j][r] + bv;
        if (obf) Cb[orow * (size_t)ldc + col] = f2bf(v);
        else     Cf[orow * (size_t)ldc + col] = v;
      }
    }
  }
}

// ---- per-quarter fence-free barrier (R10 protocol at 128-block scale) ----
__device__ __forceinline__ void gridbar(unsigned* flags, unsigned* genArr, int lb, unsigned epoch) {
  asm volatile("s_waitcnt vmcnt(0)" ::: "memory");
  __syncthreads();
  const int tid = threadIdx.x;
  if (tid == 0) st_u32(flags + lb * 32, epoch);
  if (lb == 0) {
    if (tid < 128)
      while (ld_u32(flags + tid * 32) < epoch) __builtin_amdgcn_s_sleep(1);
    __syncthreads();
    if (tid < 16) st_u32(genArr + tid * 32, epoch);
  } else if (tid == 0) {
    while (ld_u32(genArr + (lb & 15) * 32) < epoch) __builtin_amdgcn_s_sleep(1);
  }
  __syncthreads();
}

// ---- persistent recurrence: FOUR independent quarter-pipelines (8 b each),
//      128 blocks x 3 phases/step with private flags -> deeper anti-phase overlap ----
__global__ __launch_bounds__(256, 1) void k_recur(
    const ushort* __restrict__ Wqh,   // [5120][1024] bf16
    const ushort* __restrict__ encU,  // [32*128][1024] bf16
    const ushort* __restrict__ encW,  // [32*128][4096] bf16
    const float*  __restrict__ embG,  // [64*32][4096] f32
    const float*  __restrict__ Va,    // [1024]
    const float*  __restrict__ ec,    // [32*1024] encoder_cell
    float* __restrict__ hW,           // [32][5120] f32 (coherent)
    float* __restrict__ sc,           // [32][128] (coherent)
    unsigned* __restrict__ h_u32,     // [32][512] packed bf16 pairs (coherent)
    ushort* __restrict__ hall,        // [64][32][1024] bf16
    unsigned* __restrict__ flags, unsigned* __restrict__ genArr) {
  const int bid = blockIdx.x;
  const int quarter = bid >> 7;        // 0..3
  const int lb = bid & 127;            // block id within quarter
  const int hb0 = quarter * 8;         // first b of this quarter
  unsigned* flagsH = flags + quarter * (128 * 32);
  unsigned* genH   = genArr + quarter * (16 * 32);
  const int tid = threadIdx.x;
  const int lane = tid & 63, w = tid >> 6;
  __shared__ float wlds[4][8][33];
  __shared__ float red[128], wt[TE], gp[4][64];
  __shared__ float cpart[8][4][8][8];   // [tq][gate][oct][col]
  unsigned epoch = 0;

  // phase-C identity (fixed) + register-resident c state (1 unit/thread)
  const int b3 = hb0 + (lb >> 4), u0 = (lb & 15) * 64;
  float c_r = 0.f;
  if (tid < 64) c_r = ec[b3 * HH + u0 + tid];
  // phase-B identity
  const int bb = b3, tc = lb & 15;

  for (int t = 0; t < NT; ++t) {
    // ---- phase A: hW[hb0..hb0+7][n] = h @ [Wa;W_hh]^T; 160 virtual 32-col tiles
    //      over 128 blocks (M=8 dup-row MFMA, k-split 4 across waves, LDS reduce) ----
    for (int tile = lb; tile < 160; tile += 128) {
      const int n0 = tile * 32;
      const int kb = w * 256;
      const int r15 = lane & 15, ko = (lane >> 4) * 8;
      const char* hbase0 = (const char*)h_u32 + (size_t)(hb0 + (r15 & 7)) * 2048
                         + (size_t)(kb + ko) * 2;
      const ushort* B0 = Wqh + (size_t)(n0 + r15) * HH + kb + ko;
      const ushort* B1 = B0 + 16 * HH;
      fx4 a00 = {}, a01 = {};
#pragma unroll
      for (int hf = 0; hf < 2; ++hf) {
        union { ux4 u; bh8 b; } h0[4];
        const char* p0 = hbase0 + hf * 256;
        asm volatile(
          "global_load_dwordx4 %0, %4, off sc0 sc1\n\t"
          "global_load_dwordx4 %1, %4, off offset:64 sc0 sc1\n\t"
          "global_load_dwordx4 %2, %4, off offset:128 sc0 sc1\n\t"
          "global_load_dwordx4 %3, %4, off offset:192 sc0 sc1\n\t"
          "s_waitcnt vmcnt(0)"
          : "=&v"(h0[0].u), "=&v"(h0[1].u), "=&v"(h0[2].u), "=&v"(h0[3].u)
          : "v"(p0));
#pragma unroll
        for (int ks = 0; ks < 4; ++ks) {
          const int k = (hf * 4 + ks) * 32;
          bh8 bv0 = *(const bh8*)(B0 + k);
          bh8 bv1 = *(const bh8*)(B1 + k);
          a00 = __builtin_amdgcn_mfma_f32_16x16x32_bf16(h0[ks].b, bv0, a00, 0, 0, 0);
          a01 = __builtin_amdgcn_mfma_f32_16x16x32_bf16(h0[ks].b, bv1, a01, 0, 0, 0);
        }
      }
      const int rr = (lane >> 4) * 4;
#pragma unroll
      for (int r = 0; r < 4; ++r) {
        const int row = rr + r;
        if (row < 8) {
          wlds[w][row][r15]      = a00[r];
          wlds[w][row][r15 + 16] = a01[r];
        }
      }
      __syncthreads();
      {
        const int row = tid >> 5, c0 = tid & 31;
        float s = (wlds[0][row][c0] + wlds[1][row][c0])
                + (wlds[2][row][c0] + wlds[3][row][c0]);
        asm volatile("global_store_dword %0, %1, off sc0 sc1"
                     :: "v"(&hW[(size_t)(hb0 + row) * WQN + n0 + c0]), "v"(s) : "memory");
      }
      __syncthreads();
    }
    gridbar(flagsH, genH, lb, ++epoch);

    // ---- phase B: scores (128 blocks: 8 b x 16 t-chunks of 8; wave does 2 t) ----
    {
      union { ux4 u; float f[4]; } q0, q1, q2, q3;
      const float* qp0 = &hW[(size_t)bb * WQN + lane * 8];
      const float* qp1 = &hW[(size_t)bb * WQN + 512 + lane * 8];
      asm volatile(
        "global_load_dwordx4 %0, %4, off sc0 sc1\n\t"
        "global_load_dwordx4 %1, %4, off offset:16 sc0 sc1\n\t"
        "global_load_dwordx4 %2, %5, off sc0 sc1\n\t"
        "global_load_dwordx4 %3, %5, off offset:16 sc0 sc1\n\t"
        "s_waitcnt vmcnt(0)"
        : "=&v"(q0.u), "=&v"(q1.u), "=&v"(q2.u), "=&v"(q3.u)
        : "v"(qp0), "v"(qp1));
      float qr[16], vr[16];
#pragma unroll
      for (int j = 0; j < 4; ++j) {
        qr[j] = q0.f[j]; qr[4 + j] = q1.f[j];
        qr[8 + j] = q2.f[j]; qr[12 + j] = q3.f[j];
      }
#pragma unroll
      for (int c = 0; c < 2; ++c) {
        const int h0 = c * 512 + lane * 8;
        float4 va = *(const float4*)(Va + h0);
        float4 vb = *(const float4*)(Va + h0 + 4);
        vr[c*8+0] = va.x; vr[c*8+1] = va.y; vr[c*8+2] = va.z; vr[c*8+3] = va.w;
        vr[c*8+4] = vb.x; vr[c*8+5] = vb.y; vr[c*8+6] = vb.z; vr[c*8+7] = vb.w;
      }
#pragma unroll
      for (int it = 0; it < 2; ++it) {
        const int tt = tc * 8 + w * 2 + it;
        const ushort* ep = encU + (size_t)(bb * TE + tt) * HH;
        float a = 0.f;
#pragma unroll
        for (int c = 0; c < 2; ++c) {
          bh8 e8 = *(const bh8*)(ep + c * 512 + lane * 8);
#pragma unroll
          for (int j = 0; j < 8; ++j)
            a += tanh_fast(qr[c * 8 + j] + bf2f((ushort)e8[j])) * vr[c * 8 + j];
        }
#pragma unroll
        for (int s2 = 32; s2 > 0; s2 >>= 1) a += __shfl_xor(a, s2);
        if (lane == 0) st_f32(&sc[bb * TE + tt], a);
      }
    }
    gridbar(flagsH, genH, lb, ++epoch);

    // ---- phase C: softmax + encW weighted gates + LSTM (128 blocks: 8 b x 16 u-chunks) ----
    {
      const float sv = (tid < TE) ? ld_f32(&sc[b3 * TE + tid]) : -1e30f;
      if (tid < 128) red[tid] = sv;
      __syncthreads();
      for (int st = 64; st > 0; st >>= 1) {
        if (tid < st) red[tid] = fmaxf(red[tid], red[tid + st]);
        __syncthreads();
      }
      const float mx = red[0];
      __syncthreads();
      const float ev = (tid < TE) ? __expf(sv - mx) : 0.f;
      if (tid < 128) { wt[tid] = ev; red[tid] = ev; }
      __syncthreads();
      for (int st = 64; st > 0; st >>= 1) {
        if (tid < st) red[tid] += red[tid + st];
        __syncthreads();
      }
      const float inv = 1.f / red[0];
      __syncthreads();
      // weighted encW sum: thread = (oct 8cols, gate, tq 16t); 16B loads, full unroll
      const int oct = tid & 7, g = (tid >> 3) & 3, tq = tid >> 5;
      const ushort* base = encW + (size_t)(b3 * TE + tq * 16) * GG + g * 1024 + u0 + oct * 8;
      float a8[8] = {};
#pragma unroll
      for (int j = 0; j < 16; ++j) {
        bh8 e8 = *(const bh8*)(base + (size_t)j * GG);
        const float wv = wt[tq * 16 + j];
#pragma unroll
        for (int q = 0; q < 8; ++q) a8[q] += wv * bf2f((ushort)e8[q]);
      }
#pragma unroll
      for (int q = 0; q < 8; ++q) cpart[tq][g][oct][q] = a8[q];
      __syncthreads();
      // reduce 8 tq-partials + embG + hW(Whh) -> gp
      {
        const int c = tid & 63, g2 = tid >> 6;
        float s = 0.f;
#pragma unroll
        for (int q = 0; q < 8; ++q) s += cpart[q][g2][c >> 3][c & 7];
        s *= inv;
        const int cl = g2 * 1024 + u0 + c;
        s += embG[(size_t)(t * NB + b3) * GG + cl];
        float hv;
        asm volatile("global_load_dword %0, %1, off sc0 sc1\n\ts_waitcnt vmcnt(0)"
                     : "=&v"(hv) : "v"(&hW[(size_t)b3 * WQN + HH + cl]));
        gp[g2][c] = s + hv;
      }
      __syncthreads();
      // LSTM pointwise (c in registers, 1 unit/thread)
      if (tid < 64) {
        const float gi = gp[0][tid], gf = gp[1][tid];
        const float gg = gp[2][tid], go = gp[3][tid];
        const float cn = sigf(gf) * c_r + sigf(gi) * tanh_fast(gg);
        c_r = cn;
        const float hn = sigf(go) * tanh_fast(cn);
        const float hn_p = __shfl_xor(hn, 1);
        if ((tid & 1) == 0) {
          const ushort hb = f2bf(hn), hb1 = f2bf(hn_p);
          st_u32(&h_u32[b3 * 512 + ((u0 + tid) >> 1)],
                 (unsigned)hb | ((unsigned)hb1 << 16));
          *(ushort2*)(hall + (size_t)t * (NB * HH) + b3 * HH + u0 + tid) = make_ushort2(hb, hb1);
        }
      }
    }
    gridbar(flagsH, genH, lb, ++epoch);
  }
}

// Register-resident log-softmax: 1024 threads/row, 8 float4/thread, 1 read + 1 write
__global__ __launch_bounds__(1024, 1) void k_logsoftmax(float* __restrict__ out) {
  const size_t row = blockIdx.x;
  float* p = out + row * VV;
  const int tid = threadIdx.x;
  const int lane = tid & 63, wv = tid >> 6;
  __shared__ float sm[16], ss[16], bc[2];
  float4 v[8];
  const int nj = (tid < 832) ? 8 : 7;   // 8000 float4 over 1024 threads
  float m = -1e30f, s = 0.f;
  for (int j = 0; j < nj; ++j) {
    v[j] = *(const float4*)(p + (size_t)(j * 1024 + tid) * 4);
    float m4 = fmaxf(fmaxf(v[j].x, v[j].y), fmaxf(v[j].z, v[j].w));
    float nm = fmaxf(m, m4);
    s = s * __expf(m - nm) + __expf(v[j].x - nm) + __expf(v[j].y - nm)
        + __expf(v[j].z - nm) + __expf(v[j].w - nm);
    m = nm;
  }
  // wave reduce (m,s)
#pragma unroll
  for (int st = 32; st > 0; st >>= 1) {
    float mo = __shfl_xor(m, st), so = __shfl_xor(s, st);
    float m2 = fmaxf(m, mo);
    s = s * __expf(m - m2) + so * __expf(mo - m2);
    m = m2;
  }
  if (lane == 0) { sm[wv] = m; ss[wv] = s; }
  __syncthreads();
  if (tid == 0) {
    float M = sm[0], S = ss[0];
#pragma unroll
    for (int i = 1; i < 16; ++i) {
      float m2 = fmaxf(M, sm[i]);
      S = S * __expf(M - m2) + ss[i] * __expf(sm[i] - m2);
      M = m2;
    }
    bc[0] = M; bc[1] = S;
  }
  __syncthreads();
  const float L = bc[0] + logf(bc[1]);
  for (int j = 0; j < nj; ++j) {
    float4 x = v[j];
    x.x -= L; x.y -= L; x.z -= L; x.w -= L;
    *(float4*)(p + (size_t)(j * 1024 + tid) * 4) = x;
  }
}

extern "C" void kernel_launch(void* const* d_in, const int* in_sizes, int n_in,
                              void* d_out, int out_size, void* d_ws, size_t ws_size,
                              hipStream_t stream) {
  const float* enc   = (const float*)d_in[0];   // [32][128][1024]
  const float* ehid  = (const float*)d_in[1];   // [1][32][1024]
  const float* ecell = (const float*)d_in[2];
  const int*   tgt   = (const int*)d_in[3];     // [32][64]
  const float* etab  = (const float*)d_in[4];   // [32000][512]
  const float* Wa    = (const float*)d_in[5];   // [1024][1024]
  const float* Ua    = (const float*)d_in[6];
  const float* Va_w  = (const float*)d_in[7];   // [1][1024]
  // d_in[8] = Va_b: softmax-invariant constant, dropped
  const float* W_ih  = (const float*)d_in[9];   // [4096][1536]
  const float* W_hh  = (const float*)d_in[10];  // [4096][1024]
  const float* b_ih  = (const float*)d_in[11];
  const float* b_hh  = (const float*)d_in[12];
  const float* fc_w  = (const float*)d_in[13];  // [32000][1024]
  const float* fc_b  = (const float*)d_in[14];
  float* out = (float*)d_out;                   // [32][64][32000]
  float* ws = (float*)d_ws;

  // ---- workspace layout (float offsets), ~115.4 MB (R10 layout) ----
  ushort* encW_bf = (ushort*)ws;                    // [4096][4096] bf16
  float*  embG    = ws + 8388608;                   // [2048][4096] f32
  ushort* fcw_bf  = (ushort*)ws;                    // [32000][1024] bf16 AFTER recurrence
  ushort* Wqh_bf  = (ushort*)(ws + 16777216);       // [5120][1024] bf16
  ushort* encU_bf = (ushort*)(ws + 19398656);       // [4096][1024] bf16
  // precompute scratch region [21495808 .. 27262976):
  ushort* enc_bf  = (ushort*)(ws + 21495808);       // [4096][1024] bf16 (precompute only)
  ushort* Wihc_bf = (ushort*)(ws + 23592960);       // [4096][1024] bf16 (precompute only)
  ushort* Ua_bf   = (ushort*)(ws + 25690112);       // [1024][1024] (precompute only)
  ushort* emb_bf  = (ushort*)(ws + 26214400);       // [2048][512]  (precompute only)
  ushort* WihE_bf = (ushort*)(ws + 26738688);       // [4096][512]  (precompute only)
  // recurrence overlays (precompute scratch dead by then):
  float*  hW      = ws + 21495808;                  // [32][5120] f32 coherent
  float*  sc      = ws + 21659648;                  // [32][128] coherent
  unsigned* h_u32 = (unsigned*)(ws + 21663744);     // [32][512] packed bf16 coherent
  unsigned* flags = (unsigned*)(ws + 27300000);     // [4][128*32] arrival flags
  unsigned* genArr= (unsigned*)(ws + 27316384);     // [4][16*32] gen copies
  ushort* hall_bf = (ushort*)(ws + 27787264);       // [64][32][1024] -> ends 28,835,840

  // ---- precompute ----
  k_emb<<<4096, 256, 0, stream>>>(tgt, etab, emb_bf);
  k_f2b<<<4096, 256, 0, stream>>>(enc, enc_bf, 1048576);
  k_f2b<<<1024, 256, 0, stream>>>(Ua, Ua_bf, 262144);
  k_f2b<<<1024, 256, 0, stream>>>(Wa, Wqh_bf, 262144);                      // rows 0..1023
  k_f2b<<<4096, 256, 0, stream>>>(W_hh, Wqh_bf + 1024 * HH, 1048576);       // rows 1024..5119
  k_f2b_s<<<4096, 256, 0, stream>>>(W_ih, 1536, 512, 256, Wihc_bf, 1048576);
  k_f2b_s<<<2048, 256, 0, stream>>>(W_ih, 1536, 0, 128, WihE_bf, 524288);
  // encU_bf = bf16(enc @ Ua^T): M=4096 N=1024 K=1024
  k_gemm_bf16<<<dim3(8, 32), 256, 0, stream>>>(enc_bf, HH, Ua_bf, HH, nullptr, nullptr,
                                               encU_bf, HH, HH, 0, 1, 0);
  // encW_bf = bf16(enc @ W_ih[:,512:]^T): M=4096 N=4096 K=1024
  k_gemm_bf16<<<dim3(32, 32), 256, 0, stream>>>(enc_bf, HH, Wihc_bf, HH, nullptr, nullptr,
                                                encW_bf, GG, HH, 0, 1, 0);
  // embG = emb @ W_ih[:,:512]^T + b_ih + b_hh: M=2048 N=4096 K=512 (f32 out)
  k_gemm_bf16<<<dim3(32, 16), 256, 0, stream>>>(emb_bf, EE, WihE_bf, EE, b_ih, b_hh,
                                                embG, GG, EE, 0, 0, 0);
  // barrier state + h init
  (void)hipMemsetAsync(flags, 0, (4 * 128 * 32 + 4 * 16 * 32) * sizeof(unsigned), stream);
  k_init<<<64, 256, 0, stream>>>(ehid, h_u32);

  // ---- recurrence: ONE persistent kernel, four independent 128-block quarters ----
  k_recur<<<NBLK, 256, 0, stream>>>(Wqh_bf, encU_bf, encW_bf, embG, Va_w, ecell,
                                    hW, sc, h_u32, hall_bf, flags, genArr);

  // ---- output projection + log-softmax ----
  k_f2b<<<32000, 256, 0, stream>>>(fc_w, fcw_bf, 8192000);
  k_gemm_bf16<<<dim3(250, 16), 256, 0, stream>>>(hall_bf, HH, fcw_bf, HH, fc_b, nullptr,
                                                 out, VV, HH, 1, 0, 1);
  k_logsoftmax<<<2048, 1024, 0, stream>>>(out);
}

// Round 17
// 1815.016 us; speedup vs baseline: 1.1301x; 1.1301x over previous
//
#include <hip/hip_runtime.h>
#include <math.h>

// Problem constants
#define NB 32      // batch
#define TE 128     // encoder length
#define NT 64      // decoder steps
#define HH 1024    // hidden
#define EE 512     // embed dim
#define VV 32000   // vocab
#define GG 4096    // 4*H
#define WQN 5120   // Wa(1024) + W_hh(4096) output cols
#define NBLK 512   // two independent 256-block half-pipelines

typedef __attribute__((ext_vector_type(8))) short bh8;     // 8 bf16
typedef __attribute__((ext_vector_type(4))) float fx4;     // MFMA accumulator
typedef __attribute__((ext_vector_type(4))) unsigned ux4;  // 16B raw
typedef __attribute__((ext_vector_type(4))) float fv4;     // 16B float (asm-safe)

__device__ __forceinline__ float tanh_fast(float x) {
  float e = __expf(2.f * x);
  return 1.f - 2.f / (e + 1.f);
}
__device__ __forceinline__ float sigf(float x) { return 1.f / (1.f + __expf(-x)); }
__device__ __forceinline__ ushort f2bf(float x) {
  union { float f; unsigned u; } v; v.f = x;
  unsigned r = v.u + 0x7fffu + ((v.u >> 16) & 1u);
  return (ushort)(r >> 16);
}
__device__ __forceinline__ float bf2f(ushort u) {
  return __uint_as_float(((unsigned)u) << 16);
}

// agent-scope relaxed atomics for small scattered coherent ops
__device__ __forceinline__ void st_f32(float* p, float v) {
  __hip_atomic_store(p, v, __ATOMIC_RELAXED, __HIP_MEMORY_SCOPE_AGENT);
}
__device__ __forceinline__ float ld_f32(const float* p) {
  return __hip_atomic_load(p, __ATOMIC_RELAXED, __HIP_MEMORY_SCOPE_AGENT);
}
__device__ __forceinline__ void st_u32(unsigned* p, unsigned v) {
  __hip_atomic_store(p, v, __ATOMIC_RELAXED, __HIP_MEMORY_SCOPE_AGENT);
}
__device__ __forceinline__ unsigned ld_u32(const unsigned* p) {
  return __hip_atomic_load(p, __ATOMIC_RELAXED, __HIP_MEMORY_SCOPE_AGENT);
}

// h_u32 <- packed bf16 pairs of encoder_hidden[0]
__global__ void k_init(const float* __restrict__ eh, unsigned* __restrict__ h_u32) {
  int i = blockIdx.x * 256 + threadIdx.x;  // 16384
  float a = eh[i * 2], b = eh[i * 2 + 1];
  h_u32[i] = (unsigned)f2bf(a) | ((unsigned)f2bf(b) << 16);
}

// emb_bf[t*NB+b][e] = bf16(emb_table[tok(t,b)][e]); padding_idx=0 -> 0; tok(0,b)=SOS=1
__global__ void k_emb(const int* __restrict__ tgt, const float* __restrict__ etab,
                      ushort* __restrict__ emb_bf) {
  int idx = blockIdx.x * 256 + threadIdx.x;  // 1048576
  int e = idx & (EE - 1);
  int tb = idx >> 9;
  int b = tb & (NB - 1);
  int t = tb >> 5;
  int tok = (t == 0) ? 1 : tgt[b * NT + (t - 1)];
  emb_bf[idx] = (tok == 0) ? (ushort)0 : f2bf(etab[(size_t)tok * EE + e]);
}

__global__ void k_f2b(const float* __restrict__ s, ushort* __restrict__ d, int n4) {
  int i = blockIdx.x * 256 + threadIdx.x;
  if (i >= n4) return;
  float4 v = *(const float4*)(s + (size_t)i * 4);
  *(ushort4*)(d + (size_t)i * 4) = make_ushort4(f2bf(v.x), f2bf(v.y), f2bf(v.z), f2bf(v.w));
}

__global__ void k_f2b_s(const float* __restrict__ s, int ld, int off, int w4,
                        ushort* __restrict__ d, int n) {
  int i = blockIdx.x * 256 + threadIdx.x;
  if (i >= n) return;
  int r = i / w4, c = (i - r * w4) * 4;
  float4 v = *(const float4*)(s + (size_t)r * ld + off + c);
  *(ushort4*)(d + (size_t)r * (w4 * 4) + c) = make_ushort4(f2bf(v.x), f2bf(v.y), f2bf(v.z), f2bf(v.w));
}

// ---- bf16 MFMA GEMM (m97 structure): 128x128 tile, BK=32, 4 waves 2x2 ----
__device__ __forceinline__ void stage_pair(const ushort* A, int lda, const ushort* B, int ldb,
    int m0, int n0, int k0, ushort* ldsA, ushort* ldsB, int tid) {
  const int w = tid >> 6;
  const int row = tid >> 2;
  const int kq = (tid & 3) * 8;
  const ushort* ga = A + (size_t)(m0 + row) * lda + k0 + kq;
  const ushort* gb = B + (size_t)(n0 + row) * ldb + k0 + kq;
  ushort* la = ldsA + w * 512;
  ushort* lb = ldsB + w * 512;
  __builtin_amdgcn_global_load_lds((const __attribute__((address_space(1))) void*)ga,
      (__attribute__((address_space(3))) void*)la, 16, 0, 0);
  __builtin_amdgcn_global_load_lds((const __attribute__((address_space(1))) void*)(ga + (size_t)64 * lda),
      (__attribute__((address_space(3))) void*)(la + 2048), 16, 0, 0);
  __builtin_amdgcn_global_load_lds((const __attribute__((address_space(1))) void*)gb,
      (__attribute__((address_space(3))) void*)lb, 16, 0, 0);
  __builtin_amdgcn_global_load_lds((const __attribute__((address_space(1))) void*)(gb + (size_t)64 * ldb),
      (__attribute__((address_space(3))) void*)(lb + 2048), 16, 0, 0);
}

__global__ __launch_bounds__(256) void k_gemm_bf16(
    const ushort* __restrict__ A, int lda,
    const ushort* __restrict__ B, int ldb,
    const float* __restrict__ b1, const float* __restrict__ b2,
    void* __restrict__ Cv, int ldc, int K, int perm, int obf, int swz) {
  __shared__ ushort lds[2][2][4096];
  const int tid = threadIdx.x;
  const int lane = tid & 63, w = tid >> 6;
  int m0, n0;
  if (swz) {
    const int bid = blockIdx.y * gridDim.x + blockIdx.x;
    m0 = (bid & 15) * 128;
    n0 = (bid >> 4) * 128;
  } else {
    m0 = blockIdx.y * 128;
    n0 = blockIdx.x * 128;
  }
  const int wm = (w >> 1) * 64, wn = (w & 1) * 64;
  fx4 acc[4][4] = {};
  stage_pair(A, lda, B, ldb, m0, n0, 0, lds[0][0], lds[0][1], tid);
  __syncthreads();
  const int nk = K >> 5;
  const int ko = (lane >> 4) * 8;
  const int rA = wm + (lane & 15);
  const int rB = wn + (lane & 15);
  for (int ks = 0; ks < nk; ++ks) {
    const int cur = ks & 1;
    if (ks + 1 < nk)
      stage_pair(A, lda, B, ldb, m0, n0, (ks + 1) << 5, lds[cur ^ 1][0], lds[cur ^ 1][1], tid);
    bh8 af[4], bfr[4];
#pragma unroll
    for (int f = 0; f < 4; ++f) {
      af[f]  = *(const bh8*)(&lds[cur][0][(rA + f * 16) * 32 + ko]);
      bfr[f] = *(const bh8*)(&lds[cur][1][(rB + f * 16) * 32 + ko]);
    }
#pragma unroll
    for (int i = 0; i < 4; ++i)
#pragma unroll
      for (int j = 0; j < 4; ++j)
        acc[i][j] = __builtin_amdgcn_mfma_f32_16x16x32_bf16(af[i], bfr[j], acc[i][j], 0, 0, 0);
    __syncthreads();
  }
  float* Cf = (float*)Cv;
  ushort* Cb = (ushort*)Cv;
#pragma unroll
  for (int j = 0; j < 4; ++j) {
    const int col = n0 + wn + j * 16 + (lane & 15);
    const float bv = (b1 ? b1[col] : 0.f) + (b2 ? b2[col] : 0.f);
#pragma unroll
    for (int i = 0; i < 4; ++i) {
      const int mb = m0 + wm + i * 16 + (lane >> 4) * 4;
#pragma unroll
      for (int r = 0; r < 4; ++r) {
        const int m = mb + r;
        const size_t orow = perm ? ((size_t)(m & 31) * 64 + (m >> 5)) : (size_t)m;
        const float v = acc[i][j][r] + bv;
        if (obf) Cb[orow * (size_t)ldc + col] = f2bf(v);
        else     Cf[orow * (size_t)ldc + col] = v;
      }
    }
  }
}

// ---- per-half fence-free barrier (R10 protocol at 256-block scale) ----
__device__ __forceinline__ void gridbar(unsigned* flags, unsigned* genArr, int lb, unsigned epoch) {
  asm volatile("s_waitcnt vmcnt(0)" ::: "memory");
  __syncthreads();
  const int tid = threadIdx.x;
  if (tid == 0) st_u32(flags + lb * 32, epoch);
  if (lb == 0) {
    while (ld_u32(flags + tid * 32) < epoch) __builtin_amdgcn_s_sleep(1);
    __syncthreads();
    if (tid < 16) st_u32(genArr + tid * 32, epoch);
  } else if (tid == 0) {
    while (ld_u32(genArr + (lb & 15) * 32) < epoch) __builtin_amdgcn_s_sleep(1);
  }
  __syncthreads();
}

// ---- persistent recurrence: TWO independent half-pipelines (b 0..15 | b 16..31),
//      each 256 blocks x 3 phases/step with private flags -> anti-phase overlap ----
__global__ __launch_bounds__(256, 1) void k_recur(
    const ushort* __restrict__ Wqh,   // [5120][1024] bf16
    const ushort* __restrict__ encU,  // [32*128][1024] bf16
    const ushort* __restrict__ encW,  // [32*128][4096] bf16
    const float*  __restrict__ embG,  // [64*32][4096] f32
    const float*  __restrict__ Va,    // [1024]
    const float*  __restrict__ ec,    // [32*1024] encoder_cell
    float* __restrict__ hW,           // [32][5120] f32 (coherent)
    float* __restrict__ sc,           // [32][128] (coherent)
    unsigned* __restrict__ h_u32,     // [32][512] packed bf16 pairs (coherent)
    ushort* __restrict__ hall,        // [64][32][1024] bf16
    unsigned* __restrict__ flags, unsigned* __restrict__ genArr) {
  const int bid = blockIdx.x;
  const int half = bid >> 8;          // 0 or 1
  const int lb = bid & 255;           // block id within half
  const int hb0 = half * 16;          // first b of this half
  unsigned* flagsH = flags + half * (256 * 32);
  unsigned* genH   = genArr + half * (16 * 32);
  const int tid = threadIdx.x;
  const int lane = tid & 63, w = tid >> 6;
  __shared__ float wlds[4][16][33];
  __shared__ float red[128], wt[TE], gp[4][64];
  __shared__ float cpart[8][4][8][8];   // [tq][gate][oct][col]
  unsigned epoch = 0;

  // phase-C identity (fixed) + register-resident c state (1 unit/thread)
  const int b3 = hb0 + (lb >> 4), u0 = (lb & 15) * 64;
  float c_r = 0.f;
  if (tid < 64) c_r = ec[b3 * HH + u0 + tid];
  // phase-B identity
  const int bb = b3, tc = lb & 15;

  for (int t = 0; t < NT; ++t) {
    // ---- phase A: hW[hb0..hb0+15][n] = h @ [Wa;W_hh]^T (lb 0..159, 32 n-cols;
    //      M=16, k-split 4 across waves, LDS-reduced, 16B coherent h loads) ----
    if (lb < 160) {
      const int n0 = lb * 32;
      const int kb = w * 256;
      const int r15 = lane & 15, ko = (lane >> 4) * 8;
      const char* hbase0 = (const char*)h_u32 + (size_t)(hb0 + r15) * 2048 + (size_t)(kb + ko) * 2;
      const ushort* B0 = Wqh + (size_t)(n0 + r15) * HH + kb + ko;
      const ushort* B1 = B0 + 16 * HH;
      fx4 a00 = {}, a01 = {};
#pragma unroll
      for (int hf = 0; hf < 2; ++hf) {
        union { ux4 u; bh8 b; } h0[4];
        const char* p0 = hbase0 + hf * 256;
        asm volatile(
          "global_load_dwordx4 %0, %4, off sc0 sc1\n\t"
          "global_load_dwordx4 %1, %4, off offset:64 sc0 sc1\n\t"
          "global_load_dwordx4 %2, %4, off offset:128 sc0 sc1\n\t"
          "global_load_dwordx4 %3, %4, off offset:192 sc0 sc1\n\t"
          "s_waitcnt vmcnt(0)"
          : "=&v"(h0[0].u), "=&v"(h0[1].u), "=&v"(h0[2].u), "=&v"(h0[3].u)
          : "v"(p0));
#pragma unroll
        for (int ks = 0; ks < 4; ++ks) {
          const int k = (hf * 4 + ks) * 32;
          bh8 bv0 = *(const bh8*)(B0 + k);
          bh8 bv1 = *(const bh8*)(B1 + k);
          a00 = __builtin_amdgcn_mfma_f32_16x16x32_bf16(h0[ks].b, bv0, a00, 0, 0, 0);
          a01 = __builtin_amdgcn_mfma_f32_16x16x32_bf16(h0[ks].b, bv1, a01, 0, 0, 0);
        }
      }
      const int rr = (lane >> 4) * 4;
#pragma unroll
      for (int r = 0; r < 4; ++r) {
        wlds[w][rr + r][r15]      = a00[r];
        wlds[w][rr + r][r15 + 16] = a01[r];
      }
      __syncthreads();
      if (tid < 128) {
        const int row = tid >> 3, c0 = (tid & 7) * 4;
        fv4 s4;
        s4.x = wlds[0][row][c0+0] + wlds[1][row][c0+0] + wlds[2][row][c0+0] + wlds[3][row][c0+0];
        s4.y = wlds[0][row][c0+1] + wlds[1][row][c0+1] + wlds[2][row][c0+1] + wlds[3][row][c0+1];
        s4.z = wlds[0][row][c0+2] + wlds[1][row][c0+2] + wlds[2][row][c0+2] + wlds[3][row][c0+2];
        s4.w = wlds[0][row][c0+3] + wlds[1][row][c0+3] + wlds[2][row][c0+3] + wlds[3][row][c0+3];
        asm volatile("global_store_dwordx4 %0, %1, off sc0 sc1"
                     :: "v"(&hW[(size_t)(hb0 + row) * WQN + n0 + c0]), "v"(s4) : "memory");
      }
    }
    gridbar(flagsH, genH, lb, ++epoch);

    // ---- phase B: scores (256 blocks: 16 b x 16 t-chunks of 8; wave does 2 t) ----
    {
      union { ux4 u; float f[4]; } q0, q1, q2, q3;
      const float* qp0 = &hW[(size_t)bb * WQN + lane * 8];
      const float* qp1 = &hW[(size_t)bb * WQN + 512 + lane * 8];
      asm volatile(
        "global_load_dwordx4 %0, %4, off sc0 sc1\n\t"
        "global_load_dwordx4 %1, %4, off offset:16 sc0 sc1\n\t"
        "global_load_dwordx4 %2, %5, off sc0 sc1\n\t"
        "global_load_dwordx4 %3, %5, off offset:16 sc0 sc1\n\t"
        "s_waitcnt vmcnt(0)"
        : "=&v"(q0.u), "=&v"(q1.u), "=&v"(q2.u), "=&v"(q3.u)
        : "v"(qp0), "v"(qp1));
      float qr[16], vr[16];
#pragma unroll
      for (int j = 0; j < 4; ++j) {
        qr[j] = q0.f[j]; qr[4 + j] = q1.f[j];
        qr[8 + j] = q2.f[j]; qr[12 + j] = q3.f[j];
      }
#pragma unroll
      for (int c = 0; c < 2; ++c) {
        const int h0 = c * 512 + lane * 8;
        float4 va = *(const float4*)(Va + h0);
        float4 vb = *(const float4*)(Va + h0 + 4);
        vr[c*8+0] = va.x; vr[c*8+1] = va.y; vr[c*8+2] = va.z; vr[c*8+3] = va.w;
        vr[c*8+4] = vb.x; vr[c*8+5] = vb.y; vr[c*8+6] = vb.z; vr[c*8+7] = vb.w;
      }
#pragma unroll
      for (int it = 0; it < 2; ++it) {
        const int tt = tc * 8 + w * 2 + it;
        const ushort* ep = encU + (size_t)(bb * TE + tt) * HH;
        float a = 0.f;
#pragma unroll
        for (int c = 0; c < 2; ++c) {
          bh8 e8 = *(const bh8*)(ep + c * 512 + lane * 8);
#pragma unroll
          for (int j = 0; j < 8; ++j)
            a += tanh_fast(qr[c * 8 + j] + bf2f((ushort)e8[j])) * vr[c * 8 + j];
        }
#pragma unroll
        for (int s2 = 32; s2 > 0; s2 >>= 1) a += __shfl_xor(a, s2);
        if (lane == 0) st_f32(&sc[bb * TE + tt], a);
      }
    }
    gridbar(flagsH, genH, lb, ++epoch);

    // ---- phase C: softmax + encW weighted gates + LSTM (256 blocks: 16 b x 16 u-chunks) ----
    {
      const float sv = (tid < TE) ? ld_f32(&sc[b3 * TE + tid]) : -1e30f;
      if (tid < 128) red[tid] = sv;
      __syncthreads();
      for (int st = 64; st > 0; st >>= 1) {
        if (tid < st) red[tid] = fmaxf(red[tid], red[tid + st]);
        __syncthreads();
      }
      const float mx = red[0];
      __syncthreads();
      const float ev = (tid < TE) ? __expf(sv - mx) : 0.f;
      if (tid < 128) { wt[tid] = ev; red[tid] = ev; }
      __syncthreads();
      for (int st = 64; st > 0; st >>= 1) {
        if (tid < st) red[tid] += red[tid + st];
        __syncthreads();
      }
      const float inv = 1.f / red[0];
      __syncthreads();
      // weighted encW sum: thread = (oct 8cols, gate, tq 16t); 16B loads, full unroll
      const int oct = tid & 7, g = (tid >> 3) & 3, tq = tid >> 5;
      const ushort* base = encW + (size_t)(b3 * TE + tq * 16) * GG + g * 1024 + u0 + oct * 8;
      float a8[8] = {};
#pragma unroll
      for (int j = 0; j < 16; ++j) {
        bh8 e8 = *(const bh8*)(base + (size_t)j * GG);
        const float wv = wt[tq * 16 + j];
#pragma unroll
        for (int q = 0; q < 8; ++q) a8[q] += wv * bf2f((ushort)e8[q]);
      }
#pragma unroll
      for (int q = 0; q < 8; ++q) cpart[tq][g][oct][q] = a8[q];
      __syncthreads();
      // reduce 8 tq-partials + embG + hW(Whh) -> gp
      {
        const int c = tid & 63, g2 = tid >> 6;
        float s = 0.f;
#pragma unroll
        for (int q = 0; q < 8; ++q) s += cpart[q][g2][c >> 3][c & 7];
        s *= inv;
        const int cl = g2 * 1024 + u0 + c;
        s += embG[(size_t)(t * NB + b3) * GG + cl];
        float hv;
        asm volatile("global_load_dword %0, %1, off sc0 sc1\n\ts_waitcnt vmcnt(0)"
                     : "=&v"(hv) : "v"(&hW[(size_t)b3 * WQN + HH + cl]));
        gp[g2][c] = s + hv;
      }
      __syncthreads();
      // LSTM pointwise (c in registers, 1 unit/thread)
      if (tid < 64) {
        const float gi = gp[0][tid], gf = gp[1][tid];
        const float gg = gp[2][tid], go = gp[3][tid];
        const float cn = sigf(gf) * c_r + sigf(gi) * tanh_fast(gg);
        c_r = cn;
        const float hn = sigf(go) * tanh_fast(cn);
        const float hn_p = __shfl_xor(hn, 1);
        if ((tid & 1) == 0) {
          const ushort hb = f2bf(hn), hb1 = f2bf(hn_p);
          st_u32(&h_u32[b3 * 512 + ((u0 + tid) >> 1)],
                 (unsigned)hb | ((unsigned)hb1 << 16));
          *(ushort2*)(hall + (size_t)t * (NB * HH) + b3 * HH + u0 + tid) = make_ushort2(hb, hb1);
        }
      }
    }
    gridbar(flagsH, genH, lb, ++epoch);
  }
}

// Row-wise in-place log-softmax over V (one block per output row), float4
__global__ __launch_bounds__(256) void k_logsoftmax(float* __restrict__ out) {
  const size_t row = blockIdx.x;
  float* p = out + row * VV;
  __shared__ float sm[256], ss[256];
  const int tid = threadIdx.x;
  float m = -1e30f, s = 0.f;
  for (int i = tid; i < (VV / 4); i += 256) {
    float4 x = *(const float4*)(p + (size_t)i * 4);
    float m4 = fmaxf(fmaxf(x.x, x.y), fmaxf(x.z, x.w));
    float nm = fmaxf(m, m4);
    s = s * __expf(m - nm) + __expf(x.x - nm) + __expf(x.y - nm)
        + __expf(x.z - nm) + __expf(x.w - nm);
    m = nm;
  }
  sm[tid] = m; ss[tid] = s;
  __syncthreads();
  for (int st = 128; st > 0; st >>= 1) {
    if (tid < st) {
      float m2 = fmaxf(sm[tid], sm[tid + st]);
      ss[tid] = ss[tid] * __expf(sm[tid] - m2) + ss[tid + st] * __expf(sm[tid + st] - m2);
      sm[tid] = m2;
    }
    __syncthreads();
  }
  float L = sm[0] + logf(ss[0]);
  __syncthreads();
  for (int i = tid; i < (VV / 4); i += 256) {
    float4 x = *(const float4*)(p + (size_t)i * 4);
    x.x -= L; x.y -= L; x.z -= L; x.w -= L;
    *(float4*)(p + (size_t)i * 4) = x;
  }
}

extern "C" void kernel_launch(void* const* d_in, const int* in_sizes, int n_in,
                              void* d_out, int out_size, void* d_ws, size_t ws_size,
                              hipStream_t stream) {
  const float* enc   = (const float*)d_in[0];   // [32][128][1024]
  const float* ehid  = (const float*)d_in[1];   // [1][32][1024]
  const float* ecell = (const float*)d_in[2];
  const int*   tgt   = (const int*)d_in[3];     // [32][64]
  const float* etab  = (const float*)d_in[4];   // [32000][512]
  const float* Wa    = (const float*)d_in[5];   // [1024][1024]
  const float* Ua    = (const float*)d_in[6];
  const float* Va_w  = (const float*)d_in[7];   // [1][1024]
  // d_in[8] = Va_b: softmax-invariant constant, dropped
  const float* W_ih  = (const float*)d_in[9];   // [4096][1536]
  const float* W_hh  = (const float*)d_in[10];  // [4096][1024]
  const float* b_ih  = (const float*)d_in[11];
  const float* b_hh  = (const float*)d_in[12];
  const float* fc_w  = (const float*)d_in[13];  // [32000][1024]
  const float* fc_b  = (const float*)d_in[14];
  float* out = (float*)d_out;                   // [32][64][32000]
  float* ws = (float*)d_ws;

  // ---- workspace layout (float offsets), ~115.4 MB (R10 layout) ----
  ushort* encW_bf = (ushort*)ws;                    // [4096][4096] bf16
  float*  embG    = ws + 8388608;                   // [2048][4096] f32
  ushort* fcw_bf  = (ushort*)ws;                    // [32000][1024] bf16 AFTER recurrence
  ushort* Wqh_bf  = (ushort*)(ws + 16777216);       // [5120][1024] bf16
  ushort* encU_bf = (ushort*)(ws + 19398656);       // [4096][1024] bf16
  // precompute scratch region [21495808 .. 27262976):
  ushort* enc_bf  = (ushort*)(ws + 21495808);       // [4096][1024] bf16 (precompute only)
  ushort* Wihc_bf = (ushort*)(ws + 23592960);       // [4096][1024] bf16 (precompute only)
  ushort* Ua_bf   = (ushort*)(ws + 25690112);       // [1024][1024] (precompute only)
  ushort* emb_bf  = (ushort*)(ws + 26214400);       // [2048][512]  (precompute only)
  ushort* WihE_bf = (ushort*)(ws + 26738688);       // [4096][512]  (precompute only)
  // recurrence overlays (precompute scratch dead by then):
  float*  hW      = ws + 21495808;                  // [32][5120] f32 coherent
  float*  sc      = ws + 21659648;                  // [32][128] coherent
  unsigned* h_u32 = (unsigned*)(ws + 21663744);     // [32][512] packed bf16 coherent
  unsigned* flags = (unsigned*)(ws + 27300000);     // [2][256*32] arrival flags
  unsigned* genArr= (unsigned*)(ws + 27316384);     // [2][16*32] gen copies
  ushort* hall_bf = (ushort*)(ws + 27787264);       // [64][32][1024] -> ends 28,835,840

  // ---- precompute ----
  k_emb<<<4096, 256, 0, stream>>>(tgt, etab, emb_bf);
  k_f2b<<<4096, 256, 0, stream>>>(enc, enc_bf, 1048576);
  k_f2b<<<1024, 256, 0, stream>>>(Ua, Ua_bf, 262144);
  k_f2b<<<1024, 256, 0, stream>>>(Wa, Wqh_bf, 262144);                      // rows 0..1023
  k_f2b<<<4096, 256, 0, stream>>>(W_hh, Wqh_bf + 1024 * HH, 1048576);       // rows 1024..5119
  k_f2b_s<<<4096, 256, 0, stream>>>(W_ih, 1536, 512, 256, Wihc_bf, 1048576);
  k_f2b_s<<<2048, 256, 0, stream>>>(W_ih, 1536, 0, 128, WihE_bf, 524288);
  // encU_bf = bf16(enc @ Ua^T): M=4096 N=1024 K=1024
  k_gemm_bf16<<<dim3(8, 32), 256, 0, stream>>>(enc_bf, HH, Ua_bf, HH, nullptr, nullptr,
                                               encU_bf, HH, HH, 0, 1, 0);
  // encW_bf = bf16(enc @ W_ih[:,512:]^T): M=4096 N=4096 K=1024
  k_gemm_bf16<<<dim3(32, 32), 256, 0, stream>>>(enc_bf, HH, Wihc_bf, HH, nullptr, nullptr,
                                                encW_bf, GG, HH, 0, 1, 0);
  // embG = emb @ W_ih[:,:512]^T + b_ih + b_hh: M=2048 N=4096 K=512 (f32 out)
  k_gemm_bf16<<<dim3(32, 16), 256, 0, stream>>>(emb_bf, EE, WihE_bf, EE, b_ih, b_hh,
                                                embG, GG, EE, 0, 0, 0);
  // barrier state + h init
  (void)hipMemsetAsync(flags, 0, (512 * 32 + 32 * 32) * sizeof(unsigned), stream);
  k_init<<<64, 256, 0, stream>>>(ehid, h_u32);

  // ---- recurrence: ONE persistent kernel, two independent 256-block halves ----
  k_recur<<<NBLK, 256, 0, stream>>>(Wqh_bf, encU_bf, encW_bf, embG, Va_w, ecell,
                                    hW, sc, h_u32, hall_bf, flags, genArr);

  // ---- output projection + log-softmax ----
  k_f2b<<<32000, 256, 0, stream>>>(fc_w, fcw_bf, 8192000);
  k_gemm_bf16<<<dim3(250, 16), 256, 0, stream>>>(hall_bf, HH, fcw_bf, HH, fc_b, nullptr,
                                                 out, VV, HH, 1, 0, 1);
  k_logsoftmax<<<2048, 256, 0, stream>>>(out);
}